// Round 1
// baseline (408.572 us; speedup 1.0000x reference)
//
#include <hip/hip_runtime.h>
#include <cstdint>
#include <cstddef>

#define NN 8192
#define FIN 128
#define FOUT 64
#define BM 32                 // prep tile rows (kernel 1, unchanged)
#define AM 64                 // attn tile rows (kernel 2, new)
#define JSPLIT 8
#define JCH (NN / JSPLIT)     // 1024 columns per block
#define NCHUNK (JCH / 64)     // 16 chunks of K=64

typedef __bf16 bf16x8 __attribute__((ext_vector_type(8)));
typedef unsigned short u16x8 __attribute__((ext_vector_type(8)));
typedef float f32x4 __attribute__((ext_vector_type(4)));

__device__ __forceinline__ unsigned short f2bf(float f) {
    unsigned u = __float_as_uint(f);
    u += 0x7FFFu + ((u >> 16) & 1u);   // RNE
    return (unsigned short)(u >> 16);
}
__device__ __forceinline__ float bf2f(unsigned short b) {
    return __uint_as_float(((unsigned)b) << 16);
}

// ---------------------------------------------------------------------------
// Kernel 1: prep (unchanged — correct and small).
// x@W -> Ht (bf16, transposed [FOUT][NN]), s1, s2, and global max(s2).
// ---------------------------------------------------------------------------
__global__ __launch_bounds__(256) void gat_prep(
    const float* __restrict__ x, const float* __restrict__ W,
    const float* __restrict__ a, float* __restrict__ s1,
    float* __restrict__ s2, unsigned short* __restrict__ Ht,
    unsigned int* __restrict__ s2max_enc)
{
    __shared__ __align__(16) float Wt[FOUT][FIN + 4];
    __shared__ float wa1[FIN], wa2[FIN];
    __shared__ float ash[2 * FOUT];
    __shared__ float s2sh[BM];

    const int tid = threadIdx.x;
    const int i0 = blockIdx.x * BM;

    for (int it = 0; it < 32; ++it) {
        int idx = it * 256 + tid;
        int k = idx >> 6, t = idx & 63;
        Wt[t][k] = W[idx];
    }
    if (tid < 2 * FOUT) ash[tid] = a[tid];
    __syncthreads();

    if (tid < FIN) {
        int k = tid;
        float acc = 0.f;
        #pragma unroll 8
        for (int t = 0; t < FOUT; ++t) acc = fmaf(Wt[t][k], ash[t], acc);
        wa1[k] = acc;
    } else {
        int k = tid - FIN;
        float acc = 0.f;
        #pragma unroll 8
        for (int t = 0; t < FOUT; ++t) acc = fmaf(Wt[t][k], ash[FOUT + t], acc);
        wa2[k] = acc;
    }
    __syncthreads();

    {
        int r = tid >> 3;
        int seg = tid & 7;
        const float* xp = x + (size_t)(i0 + r) * FIN + seg * 16;
        float d1 = 0.f, d2 = 0.f;
        #pragma unroll
        for (int m = 0; m < 16; ++m) {
            float xv = xp[m];
            d1 = fmaf(xv, wa1[seg * 16 + m], d1);
            d2 = fmaf(xv, wa2[seg * 16 + m], d2);
        }
        #pragma unroll
        for (int mk = 1; mk < 8; mk <<= 1) {
            d1 += __shfl_xor(d1, mk);
            d2 += __shfl_xor(d2, mk);
        }
        if (seg == 0) {
            s1[i0 + r] = d1;
            s2[i0 + r] = d2;
            s2sh[r] = d2;
        }
    }

    {
        const int lane = tid & 63;
        const int wv = tid >> 6;
        const int ih = wv & 1, nh = wv >> 1;
        const int m = lane & 15, quad = lane >> 4;
        f32x4 hacc0 = {0.f, 0.f, 0.f, 0.f};
        f32x4 hacc1 = {0.f, 0.f, 0.f, 0.f};
        const float* xrow = x + (size_t)(i0 + ih * 16 + m) * FIN + quad * 8;
        #pragma unroll
        for (int ks = 0; ks < 4; ++ks) {
            const float* xp = xrow + ks * 32;
            u16x8 ua;
            #pragma unroll
            for (int jj = 0; jj < 8; ++jj) ua[jj] = f2bf(xp[jj]);
            bf16x8 af = __builtin_bit_cast(bf16x8, ua);
            {
                const float* wp = &Wt[nh * 32 + m][ks * 32 + quad * 8];
                u16x8 ub;
                #pragma unroll
                for (int jj = 0; jj < 8; ++jj) ub[jj] = f2bf(wp[jj]);
                bf16x8 bfr = __builtin_bit_cast(bf16x8, ub);
                hacc0 = __builtin_amdgcn_mfma_f32_16x16x32_bf16(af, bfr, hacc0, 0, 0, 0);
            }
            {
                const float* wp = &Wt[nh * 32 + 16 + m][ks * 32 + quad * 8];
                u16x8 ub;
                #pragma unroll
                for (int jj = 0; jj < 8; ++jj) ub[jj] = f2bf(wp[jj]);
                bf16x8 bfr = __builtin_bit_cast(bf16x8, ub);
                hacc1 = __builtin_amdgcn_mfma_f32_16x16x32_bf16(af, bfr, hacc1, 0, 0, 0);
            }
        }
        #pragma unroll
        for (int reg = 0; reg < 4; ++reg) {
            int irow = i0 + ih * 16 + quad * 4 + reg;
            int t0 = nh * 32 + m;
            Ht[(size_t)t0 * NN + irow] = f2bf(hacc0[reg]);
            Ht[(size_t)(t0 + 16) * NN + irow] = f2bf(hacc1[reg]);
        }
    }
    __syncthreads();
    if (tid == 0) {
        float mx = s2sh[0];
        #pragma unroll
        for (int r = 1; r < BM; ++r) mx = fmaxf(mx, s2sh[r]);
        unsigned ub = __float_as_uint(mx);
        unsigned enc = (ub & 0x80000000u) ? ~ub : (ub | 0x80000000u);
        atomicMax(s2max_enc, enc);
    }
}

// ---------------------------------------------------------------------------
// P-fragment production: 8 masked-softmax numerator values computed directly
// in MFMA A-fragment layout (row = lane&15, k = (lane>>4)*8 + jj).
// ---------------------------------------------------------------------------
__device__ __forceinline__ void make_p(const int4 A, const int4 B,
                                       const float* __restrict__ s2p,
                                       float s1r, float M,
                                       u16x8& ua, float& ps)
{
    const int av[8] = {A.x, A.y, A.z, A.w, B.x, B.y, B.z, B.w};
    #pragma unroll
    for (int jj = 0; jj < 8; ++jj) {
        float e = fmaxf(s1r + s2p[jj], 0.f);
        float pv = (av[jj] > 0) ? __expf(e - M) : 0.f;
        unsigned short qv = f2bf(pv);
        ua[jj] = qv;
        ps += bf2f(qv);
    }
}

// ---------------------------------------------------------------------------
// Kernel 2 (R4 rewrite): fused masked-softmax + PV matmul, barrier-free.
// Each wave owns 16 P-rows x all 64 output cols. Each lane computes its own
// MFMA A-fragment of P from adj/s1/s2 in registers -> no P LDS, no in-loop
// __syncthreads, no vmcnt(0) drain of the adj prefetch. adj streams once
// (256 MiB), Ht B-fragments are L2-resident.
// Grid: (NN/AM)*JSPLIT = 1024 blocks of 256 -> exactly 4 blocks/CU.
// ---------------------------------------------------------------------------
__global__ __launch_bounds__(256, 4) void gat_attn(
    const int* __restrict__ adj, const float* __restrict__ s1,
    const float* __restrict__ s2, const unsigned short* __restrict__ Ht,
    const unsigned int* __restrict__ s2max_enc,
    float* __restrict__ pacc, float* __restrict__ pl)
{
    __shared__ __align__(16) float s2sh[JCH];   // 4 KB, read-only after 1 barrier

    const int tid = threadIdx.x;
    const int bx = blockIdx.x;
    const int r = bx >> 3;            // 0..127
    const int js = bx & 7;
    const int i0 = r * AM;
    const int j0 = js * JCH;

    const int lane = tid & 63;
    const int w = tid >> 6;           // wave 0..3 -> owns rows i0+w*16 .. +15
    const int m = lane & 15;
    const int q = lane >> 4;

    const int irow = i0 + w * 16 + m; // this lane's P/adj row

    // stage s2 strip (once)
    {
        int idx = tid * 4;
        *(float4*)&s2sh[idx] = *(const float4*)(s2 + j0 + idx);
    }
    unsigned u = *s2max_enc;
    const float S2MAX = (u & 0x80000000u) ? __uint_as_float(u ^ 0x80000000u)
                                          : __uint_as_float(~u);
    const float s1r = s1[irow];
    const float M = fmaxf(0.f, s1r + S2MAX);   // upper bound of row max of e
    __syncthreads();                           // the only barrier

    // per-lane adj base: row irow, cols j0 + q*8 (+32 for the k=32..63 frag)
    const int* adjr = adj + (size_t)irow * NN + j0 + q * 8;
    // B-fragment base: Ht row t = nt*16 + m, col j0 + q*8
    const unsigned short* htb = Ht + (size_t)m * NN + j0 + q * 8;

    f32x4 acc0 = {0.f, 0.f, 0.f, 0.f};
    f32x4 acc1 = {0.f, 0.f, 0.f, 0.f};
    f32x4 acc2 = {0.f, 0.f, 0.f, 0.f};
    f32x4 acc3 = {0.f, 0.f, 0.f, 0.f};
    float ps = 0.f;

    // prefetch chunk 0 adj into registers
    int4 c0a = *(const int4*)(adjr);
    int4 c0b = *(const int4*)(adjr + 4);
    int4 c1a = *(const int4*)(adjr + 32);
    int4 c1b = *(const int4*)(adjr + 36);

    for (int c = 0; c < NCHUNK; ++c) {
        // issue next chunk's adj (HBM) — nothing drains vmcnt before use
        const int cn = (c + 1 < NCHUNK) ? c + 1 : c;
        const int* an = adjr + cn * 64;
        int4 n0a = *(const int4*)(an);
        int4 n0b = *(const int4*)(an + 4);
        int4 n1a = *(const int4*)(an + 32);
        int4 n1b = *(const int4*)(an + 36);

        // issue this chunk's 8 Ht B-fragments (L2-resident)
        const unsigned short* hb = htb + c * 64;
        bf16x8 b00 = *(const bf16x8*)(hb);                                  // nt0 ks0
        bf16x8 b01 = *(const bf16x8*)(hb + 32);                             // nt0 ks1
        bf16x8 b10 = *(const bf16x8*)(hb + (size_t)16 * NN);                // nt1 ks0
        bf16x8 b11 = *(const bf16x8*)(hb + (size_t)16 * NN + 32);
        bf16x8 b20 = *(const bf16x8*)(hb + (size_t)32 * NN);                // nt2 ks0
        bf16x8 b21 = *(const bf16x8*)(hb + (size_t)32 * NN + 32);
        bf16x8 b30 = *(const bf16x8*)(hb + (size_t)48 * NN);                // nt3 ks0
        bf16x8 b31 = *(const bf16x8*)(hb + (size_t)48 * NN + 32);

        // compute P fragments in registers (A-layout), accumulate row-sum
        const float* s2p = &s2sh[c * 64 + q * 8];
        u16x8 ua0, ua1;
        make_p(c0a, c0b, s2p,      s1r, M, ua0, ps);   // k = 0..31 slice
        make_p(c1a, c1b, s2p + 32, s1r, M, ua1, ps);   // k = 32..63 slice
        bf16x8 af0 = __builtin_bit_cast(bf16x8, ua0);
        bf16x8 af1 = __builtin_bit_cast(bf16x8, ua1);

        // PV: 16 rows x 64 cols, K=64
        acc0 = __builtin_amdgcn_mfma_f32_16x16x32_bf16(af0, b00, acc0, 0, 0, 0);
        acc1 = __builtin_amdgcn_mfma_f32_16x16x32_bf16(af0, b10, acc1, 0, 0, 0);
        acc2 = __builtin_amdgcn_mfma_f32_16x16x32_bf16(af0, b20, acc2, 0, 0, 0);
        acc3 = __builtin_amdgcn_mfma_f32_16x16x32_bf16(af0, b30, acc3, 0, 0, 0);
        acc0 = __builtin_amdgcn_mfma_f32_16x16x32_bf16(af1, b01, acc0, 0, 0, 0);
        acc1 = __builtin_amdgcn_mfma_f32_16x16x32_bf16(af1, b11, acc1, 0, 0, 0);
        acc2 = __builtin_amdgcn_mfma_f32_16x16x32_bf16(af1, b21, acc2, 0, 0, 0);
        acc3 = __builtin_amdgcn_mfma_f32_16x16x32_bf16(af1, b31, acc3, 0, 0, 0);

        c0a = n0a; c0b = n0b; c1a = n1a; c1b = n1b;
    }

    // row-sum l: combine the 4 q-lanes holding the same row
    ps += __shfl_xor(ps, 16);
    ps += __shfl_xor(ps, 32);
    if (q == 0) pl[(size_t)js * NN + irow] = ps;

    // write partial acc: C layout row = q*4+reg, col = m (per nt tile)
    const int orow = i0 + w * 16 + q * 4;
    float* pb = pacc + ((size_t)js * NN + orow) * FOUT + m;
    #pragma unroll
    for (int reg = 0; reg < 4; ++reg) {
        pb[(size_t)reg * FOUT]      = acc0[reg];
        pb[(size_t)reg * FOUT + 16] = acc1[reg];
        pb[(size_t)reg * FOUT + 32] = acc2[reg];
        pb[(size_t)reg * FOUT + 48] = acc3[reg];
    }
}

// ---------------------------------------------------------------------------
// Kernel 3: combine j-split partials: out = sum(acc) / sum(l)
// ---------------------------------------------------------------------------
__global__ __launch_bounds__(256) void gat_combine(
    const float* __restrict__ pacc, const float* __restrict__ pl,
    float* __restrict__ out)
{
    int idx = blockIdx.x * 256 + threadIdx.x;   // over NN*FOUT
    int i = idx >> 6;
    float s = 0.f, l = 0.f;
    #pragma unroll
    for (int js = 0; js < JSPLIT; ++js) {
        s += pacc[(size_t)js * NN * FOUT + idx];
        l += pl[(size_t)js * NN + i];
    }
    out[idx] = s / l;
}

// ---------------------------------------------------------------------------
extern "C" void kernel_launch(void* const* d_in, const int* in_sizes, int n_in,
                              void* d_out, int out_size, void* d_ws, size_t ws_size,
                              hipStream_t stream) {
    const float* x   = (const float*)d_in[0];
    const int*   adj = (const int*)d_in[1];
    const float* W   = (const float*)d_in[2];
    const float* a   = (const float*)d_in[3];
    float* out = (float*)d_out;

    char* ws = (char*)d_ws;
    float* s1             = (float*)(ws);                         // 32 KB
    float* s2             = (float*)(ws + 32768);                 // 32 KB
    unsigned int* s2enc   = (unsigned int*)(ws + 65536);          // 4 B (padded to 1 KB)
    unsigned short* Ht    = (unsigned short*)(ws + 66560);        // 1 MiB
    float* pacc           = (float*)(ws + 66560 + 1048576);       // 16 MiB (JSPLIT=8)
    float* pl             = (float*)(ws + 66560 + 1048576 + 16777216); // 256 KB

    hipMemsetAsync(s2enc, 0, 4, stream);
    gat_prep<<<NN / BM, 256, 0, stream>>>(x, W, a, s1, s2, Ht, s2enc);
    gat_attn<<<(NN / AM) * JSPLIT, 256, 0, stream>>>(adj, s1, s2, Ht, s2enc, pacc, pl);
    gat_combine<<<NN * FOUT / 256, 256, 0, stream>>>(pacc, pl, out);
}